// Round 4
// baseline (109.463 us; speedup 1.0000x reference)
//
#include <hip/hip_runtime.h>

#define BB 4
#define SS 4096
#define DD 64
// scale = 1/sqrt(4096), with log2(e) folded in so softmax runs in exp2 domain
#define QSCALE (0.015625f * 1.44269504088896f)

typedef __attribute__((ext_vector_type(4))) float f32x4;
typedef __attribute__((ext_vector_type(8))) short s16x8;
typedef unsigned short u16;

union frag_u { unsigned u[4]; s16x8 s; };

// Round-half-up pack of two f32 into (lo,hi) bf16 pair: 2 v_add + 1 v_perm.
__device__ __forceinline__ unsigned pack_bf16(float lo, float hi) {
    union { float f; unsigned u; } a, b; a.f = lo; b.f = hi;
    return __builtin_amdgcn_perm(b.u + 0x8000u, a.u + 0x8000u, 0x07060302u);
}

// ---- prep 1: K (fp32 row-major) -> Kbf (bf16 row-major), 8 elems/thread ----
__global__ __launch_bounds__(256) void conv_k(const float* __restrict__ K,
                                              u16* __restrict__ Kbf) {
    const long i = ((long)blockIdx.x * 256 + threadIdx.x) * 8;
    f32x4 a = *(const f32x4*)(K + i);
    f32x4 b = *(const f32x4*)(K + i + 4);
    frag_u f;
    f.u[0] = pack_bf16(a[0], a[1]);
    f.u[1] = pack_bf16(a[2], a[3]);
    f.u[2] = pack_bf16(b[0], b[1]);
    f.u[3] = pack_bf16(b[2], b[3]);
    *(s16x8*)(Kbf + i) = f.s;
}

// ---- prep 2: V (fp32 [b][s][d]) -> VT (bf16 [b][d][s]), LDS tile transpose ----
__global__ __launch_bounds__(256) void conv_vt(const float* __restrict__ V,
                                               u16* __restrict__ VT) {
    __shared__ u16 tile[64][72];
    const int b  = blockIdx.x >> 6;
    const int kt = blockIdx.x & 63;
    const int tid = threadIdx.x;
    const float* Vb = V + ((long)b * SS + kt * 64) * DD;
    {
        const int kk = tid >> 4;
        const int d4 = (tid & 15) * 4;
        #pragma unroll
        for (int p = 0; p < 4; ++p) {
            const int k = kk + p * 16;
            f32x4 v = *(const f32x4*)(Vb + k * DD + d4);
            #pragma unroll
            for (int c = 0; c < 4; ++c) {
                union { float f; unsigned u; } x; x.f = v[c];
                tile[d4 + c][k] = (u16)((x.u + 0x8000u) >> 16);
            }
        }
    }
    __syncthreads();
    {
        const int d  = tid >> 2;
        const int kg = (tid & 3) * 16;
        u16* dst = VT + ((long)b * DD + d) * SS + kt * 64 + kg;
        frag_u w0, w1;
        #pragma unroll
        for (int j = 0; j < 4; ++j) {
            w0.u[j] = (unsigned)tile[d][kg + 2 * j] | ((unsigned)tile[d][kg + 2 * j + 1] << 16);
            w1.u[j] = (unsigned)tile[d][kg + 8 + 2 * j] | ((unsigned)tile[d][kg + 9 + 2 * j] << 16);
        }
        *(s16x8*)dst = w0.s;
        *(s16x8*)(dst + 8) = w1.s;
    }
}

template<bool PRE>
__global__ __launch_bounds__(512, 8) void
attn_fwd(const float* __restrict__ Q, const float* __restrict__ K,
         const float* __restrict__ V, float* __restrict__ O,
         const u16* __restrict__ Kbf, const u16* __restrict__ VT)
{
    __shared__ float mbuf[4][16 * 68];
    __shared__ float smM[4][16];
    __shared__ float smL[4][16];

    const int tid  = threadIdx.x;
    const int w    = tid >> 6;
    const int lane = tid & 63;
    const int m    = lane & 15;
    const int g    = lane >> 4;

    const int idx = blockIdx.x;
    const int t   = 255 - (idx >> 2);
    const int b   = idx & 3;
    const int q0  = t * 16;

    const float* Qb  = Q + ((long)b * SS + q0) * DD;
    const float* Kb0 = K + (long)b * SS * DD;
    const float* Vb0 = V + (long)b * SS * DD;
    const u16* Kf0 = Kbf + ((long)b * SS) * DD + g * 8;
    const u16* Vt0 = VT + (long)b * DD * SS + (long)m * SS + g * 8;

    // ---- Q fragments (B operand of swapped QK^T), scale folded in ----
    s16x8 qf[2];
    {
        const float* qrow = Qb + m * DD + g * 8;
        #pragma unroll
        for (int kst = 0; kst < 2; ++kst) {
            f32x4 x0 = *(const f32x4*)(qrow + kst * 32);
            f32x4 x1 = *(const f32x4*)(qrow + kst * 32 + 4);
            frag_u f;
            f.u[0] = pack_bf16(x0[0] * QSCALE, x0[1] * QSCALE);
            f.u[1] = pack_bf16(x0[2] * QSCALE, x0[3] * QSCALE);
            f.u[2] = pack_bf16(x1[0] * QSCALE, x1[1] * QSCALE);
            f.u[3] = pack_bf16(x1[2] * QSCALE, x1[3] * QSCALE);
            qf[kst] = f.s;
        }
    }

    f32x4 o[4];
    #pragma unroll
    for (int dt = 0; dt < 4; ++dt) o[dt] = (f32x4){0.f, 0.f, 0.f, 0.f};
    float m_run = -1e30f, l_run = 0.f;

    const int ntiles = (q0 >> 6) + 1;
    const int q_g = q0 + m;

    for (int tile = w; tile < ntiles; tile += 8) {
        const int kvbase = tile * 64;

        // ---- S^T = K_tile · Q^T ----
        f32x4 st[4];
        #pragma unroll
        for (int mt = 0; mt < 4; ++mt) {
            st[mt] = (f32x4){0.f, 0.f, 0.f, 0.f};
            if (PRE) {
                const u16* kr = Kf0 + (long)(kvbase + mt * 16 + m) * DD;
                #pragma unroll
                for (int kst = 0; kst < 2; ++kst) {
                    s16x8 kf = *(const s16x8*)(kr + kst * 32);
                    st[mt] = __builtin_amdgcn_mfma_f32_16x16x32_bf16(kf, qf[kst], st[mt], 0, 0, 0);
                }
            } else {
                const float* kr = Kb0 + (long)(kvbase + mt * 16 + m) * DD + g * 8;
                #pragma unroll
                for (int kst = 0; kst < 2; ++kst) {
                    f32x4 x0 = *(const f32x4*)(kr + kst * 32);
                    f32x4 x1 = *(const f32x4*)(kr + kst * 32 + 4);
                    frag_u kf;
                    kf.u[0] = pack_bf16(x0[0], x0[1]);
                    kf.u[1] = pack_bf16(x0[2], x0[3]);
                    kf.u[2] = pack_bf16(x1[0], x1[1]);
                    kf.u[3] = pack_bf16(x1[2], x1[3]);
                    st[mt] = __builtin_amdgcn_mfma_f32_16x16x32_bf16(kf.s, qf[kst], st[mt], 0, 0, 0);
                }
            }
        }

        // ---- causal mask (diagonal tile only; wave-uniform branch) ----
        if (tile == ntiles - 1) {
            #pragma unroll
            for (int mt = 0; mt < 4; ++mt)
                #pragma unroll
                for (int r = 0; r < 4; ++r) {
                    const int k_g = kvbase + mt * 16 + g * 4 + r;
                    if (k_g > q_g) st[mt][r] = -1e9f;
                }
        }

        // ---- online softmax in exp2 domain; lane owns row q0+m ----
        float tm = st[0][0];
        #pragma unroll
        for (int mt = 0; mt < 4; ++mt)
            #pragma unroll
            for (int r = 0; r < 4; ++r) tm = fmaxf(tm, st[mt][r]);
        tm = fmaxf(tm, __shfl_xor(tm, 16));
        tm = fmaxf(tm, __shfl_xor(tm, 32));
        const float mnew  = fmaxf(m_run, tm);
        const float alpha = exp2f(m_run - mnew);
        float rs = 0.f;
        #pragma unroll
        for (int mt = 0; mt < 4; ++mt)
            #pragma unroll
            for (int r = 0; r < 4; ++r) {
                const float e = exp2f(st[mt][r] - mnew);
                st[mt][r] = e;
                rs += e;
            }
        rs += __shfl_xor(rs, 16);
        rs += __shfl_xor(rs, 32);
        l_run = l_run * alpha + rs;
        m_run = mnew;

        // ---- pack P pairs -> bf16 words, in-lane ----
        unsigned pk[4][2];
        #pragma unroll
        for (int mt = 0; mt < 4; ++mt) {
            pk[mt][0] = pack_bf16(st[mt][0], st[mt][1]);
            pk[mt][1] = pack_bf16(st[mt][2], st[mt][3]);
        }

        // ---- rescale O ----
        float av[4];
        #pragma unroll
        for (int r = 0; r < 4; ++r) av[r] = __shfl(alpha, 4 * g + r);
        #pragma unroll
        for (int dt = 0; dt < 4; ++dt)
            #pragma unroll
            for (int r = 0; r < 4; ++r) o[dt][r] *= av[r];

        // ---- O += P · V (A via 2-shfl relayout, dest-side select) ----
        #pragma unroll
        for (int kst = 0; kst < 2; ++kst) {
            frag_u pa;
            #pragma unroll
            for (int ww = 0; ww < 4; ++ww) {
                const int srcl = m + 16 * (2 * (g & 1) + (ww >> 1));
                const int v0 = __shfl((int)pk[2 * kst][ww & 1], srcl);
                const int v1 = __shfl((int)pk[2 * kst + 1][ww & 1], srcl);
                pa.u[ww] = (unsigned)((g & 2) ? v1 : v0);
            }
            if (PRE) {
                const u16* vr = Vt0 + kvbase + kst * 32;
                #pragma unroll
                for (int dt = 0; dt < 4; ++dt) {
                    s16x8 vb = *(const s16x8*)(vr + (long)dt * 16 * SS);
                    o[dt] = __builtin_amdgcn_mfma_f32_16x16x32_bf16(pa.s, vb, o[dt], 0, 0, 0);
                }
            } else {
                const float* vcol = Vb0 + (long)(kvbase + kst * 32 + g * 8) * DD + m;
                #pragma unroll
                for (int dt = 0; dt < 4; ++dt) {
                    const float* vc = vcol + dt * 16;
                    frag_u vb;
                    #pragma unroll
                    for (int jj = 0; jj < 4; ++jj)
                        vb.u[jj] = pack_bf16(vc[(2 * jj) * DD], vc[(2 * jj + 1) * DD]);
                    o[dt] = __builtin_amdgcn_mfma_f32_16x16x32_bf16(pa.s, vb.s, o[dt], 0, 0, 0);
                }
            }
        }
    }

    // ---- merge tree across the 8 waves ----
    for (int half = 4; half >= 1; half >>= 1) {
        if (w >= half && w < 2 * half) {
            const int slot = w - half;
            if (g == 0) { smM[slot][m] = m_run; smL[slot][m] = l_run; }
            #pragma unroll
            for (int dt = 0; dt < 4; ++dt)
                #pragma unroll
                for (int r = 0; r < 4; ++r)
                    mbuf[slot][(4 * g + r) * 68 + 16 * dt + m] = o[dt][r];
        }
        __syncthreads();
        if (w < half) {
            const float m2 = smM[w][m], l2 = smL[w][m];
            const float mn = fmaxf(m_run, m2);
            const float a1 = exp2f(m_run - mn);
            const float a2 = exp2f(m2 - mn);
            l_run = l_run * a1 + l2 * a2;
            m_run = mn;
            float av1[4], av2[4];
            #pragma unroll
            for (int r = 0; r < 4; ++r) {
                av1[r] = __shfl(a1, 4 * g + r);
                av2[r] = __shfl(a2, 4 * g + r);
            }
            #pragma unroll
            for (int dt = 0; dt < 4; ++dt)
                #pragma unroll
                for (int r = 0; r < 4; ++r)
                    o[dt][r] = o[dt][r] * av1[r] +
                               mbuf[w][(4 * g + r) * 68 + 16 * dt + m] * av2[r];
        }
        __syncthreads();
    }

    // ---- epilogue ----
    if (w == 0) {
        float lv[4];
        #pragma unroll
        for (int r = 0; r < 4; ++r) lv[r] = 1.0f / __shfl(l_run, 4 * g + r);
        float* Ob = O + ((long)b * SS + q0) * DD;
        #pragma unroll
        for (int dt = 0; dt < 4; ++dt)
            #pragma unroll
            for (int r = 0; r < 4; ++r)
                Ob[(4 * g + r) * DD + dt * 16 + m] = o[dt][r] * lv[r];
    }
}

extern "C" void kernel_launch(void* const* d_in, const int* in_sizes, int n_in,
                              void* d_out, int out_size, void* d_ws, size_t ws_size,
                              hipStream_t stream) {
    const float* Q = (const float*)d_in[0];
    const float* K = (const float*)d_in[1];
    const float* V = (const float*)d_in[2];
    float* O = (float*)d_out;
    const size_t tensor_b = (size_t)BB * SS * DD * sizeof(u16);   // 2 MiB
    if (ws_size >= 2 * tensor_b) {
        u16* Kbf = (u16*)d_ws;
        u16* VT  = (u16*)((char*)d_ws + tensor_b);
        conv_k <<<dim3(BB * SS * DD / 8 / 256), dim3(256), 0, stream>>>(K, Kbf);
        conv_vt<<<dim3(BB * (SS / 64)),        dim3(256), 0, stream>>>(V, VT);
        attn_fwd<true><<<dim3(BB * (SS / 16)), dim3(512), 0, stream>>>(Q, K, V, O, Kbf, VT);
    } else {
        attn_fwd<false><<<dim3(BB * (SS / 16)), dim3(512), 0, stream>>>(Q, K, V, O, nullptr, nullptr);
    }
}

// Round 5
// 79.695 us; speedup vs baseline: 1.3735x; 1.3735x over previous
//
#include <hip/hip_runtime.h>

#define BB 4
#define SS 4096
#define DD 64
// scale = 1/sqrt(4096), with log2(e) folded in so softmax runs in exp2 domain
#define QSCALE (0.015625f * 1.44269504088896f)

typedef __attribute__((ext_vector_type(4))) float f32x4;
typedef __attribute__((ext_vector_type(8))) short s16x8;
typedef unsigned short u16;

union frag_u { unsigned u[4]; s16x8 s; };

// Round-half-up pack of two f32 into (lo,hi) bf16 pair: 2 v_add + 1 v_perm.
__device__ __forceinline__ unsigned pack_bf16(float lo, float hi) {
    union { float f; unsigned u; } a, b; a.f = lo; b.f = hi;
    return __builtin_amdgcn_perm(b.u + 0x8000u, a.u + 0x8000u, 0x07060302u);
}

// ---- prep 1: K (fp32 row-major) -> Kbf (bf16 row-major), 8 elems/thread ----
__global__ __launch_bounds__(256) void conv_k(const float* __restrict__ K,
                                              u16* __restrict__ Kbf) {
    const long i = ((long)blockIdx.x * 256 + threadIdx.x) * 8;
    f32x4 a = *(const f32x4*)(K + i);
    f32x4 b = *(const f32x4*)(K + i + 4);
    frag_u f;
    f.u[0] = pack_bf16(a[0], a[1]);
    f.u[1] = pack_bf16(a[2], a[3]);
    f.u[2] = pack_bf16(b[0], b[1]);
    f.u[3] = pack_bf16(b[2], b[3]);
    *(s16x8*)(Kbf + i) = f.s;
}

// ---- prep 2: V (fp32 [b][s][d]) -> VT (bf16 [b][d][s]), LDS tile transpose ----
__global__ __launch_bounds__(256) void conv_vt(const float* __restrict__ V,
                                               u16* __restrict__ VT) {
    __shared__ u16 tile[64][72];
    const int b  = blockIdx.x >> 6;
    const int kt = blockIdx.x & 63;
    const int tid = threadIdx.x;
    const float* Vb = V + ((long)b * SS + kt * 64) * DD;
    {
        const int kk = tid >> 4;
        const int d4 = (tid & 15) * 4;
        #pragma unroll
        for (int p = 0; p < 4; ++p) {
            const int k = kk + p * 16;
            f32x4 v = *(const f32x4*)(Vb + k * DD + d4);
            #pragma unroll
            for (int c = 0; c < 4; ++c) {
                union { float f; unsigned u; } x; x.f = v[c];
                tile[d4 + c][k] = (u16)((x.u + 0x8000u) >> 16);
            }
        }
    }
    __syncthreads();
    {
        const int d  = tid >> 2;
        const int kg = (tid & 3) * 16;
        u16* dst = VT + ((long)b * DD + d) * SS + kt * 64 + kg;
        frag_u w0, w1;
        #pragma unroll
        for (int j = 0; j < 4; ++j) {
            w0.u[j] = (unsigned)tile[d][kg + 2 * j] | ((unsigned)tile[d][kg + 2 * j + 1] << 16);
            w1.u[j] = (unsigned)tile[d][kg + 8 + 2 * j] | ((unsigned)tile[d][kg + 9 + 2 * j] << 16);
        }
        *(s16x8*)dst = w0.s;
        *(s16x8*)(dst + 8) = w1.s;
    }
}

template<bool PRE>
__global__ __launch_bounds__(512, 4) void
attn_fwd(const float* __restrict__ Q, const float* __restrict__ K,
         const float* __restrict__ V, float* __restrict__ O,
         const u16* __restrict__ Kbf, const u16* __restrict__ VT)
{
    __shared__ float mbuf[4][16 * 68];
    __shared__ float smM[4][16];
    __shared__ float smL[4][16];

    const int tid  = threadIdx.x;
    const int w    = tid >> 6;
    const int lane = tid & 63;
    const int m    = lane & 15;
    const int g    = lane >> 4;

    const int idx = blockIdx.x;
    const int t   = 255 - (idx >> 2);
    const int b   = idx & 3;
    const int q0  = t * 16;

    const float* Qb  = Q + ((long)b * SS + q0) * DD;
    const float* Kb0 = K + (long)b * SS * DD;
    const float* Vb0 = V + (long)b * SS * DD;
    const u16* Kf0 = Kbf + ((long)b * SS) * DD + g * 8;
    const u16* Vt0 = VT + (long)b * DD * SS + (long)m * SS + g * 8;

    // ---- Q fragments (B operand of swapped QK^T), scale folded in ----
    s16x8 qf[2];
    {
        const float* qrow = Qb + m * DD + g * 8;
        #pragma unroll
        for (int kst = 0; kst < 2; ++kst) {
            f32x4 x0 = *(const f32x4*)(qrow + kst * 32);
            f32x4 x1 = *(const f32x4*)(qrow + kst * 32 + 4);
            frag_u f;
            f.u[0] = pack_bf16(x0[0] * QSCALE, x0[1] * QSCALE);
            f.u[1] = pack_bf16(x0[2] * QSCALE, x0[3] * QSCALE);
            f.u[2] = pack_bf16(x1[0] * QSCALE, x1[1] * QSCALE);
            f.u[3] = pack_bf16(x1[2] * QSCALE, x1[3] * QSCALE);
            qf[kst] = f.s;
        }
    }

    f32x4 o[4];
    #pragma unroll
    for (int dt = 0; dt < 4; ++dt) o[dt] = (f32x4){0.f, 0.f, 0.f, 0.f};
    float m_run = -1e30f, l_run = 0.f;

    const int ntiles = (q0 >> 6) + 1;
    const int q_g = q0 + m;

    for (int tile = w; tile < ntiles; tile += 8) {
        const int kvbase = tile * 64;

        f32x4 st[4];
        if (PRE) {
            // ---- batch-issue ALL K and V fragment loads (16 x 16B in flight) ----
            s16x8 kf[4][2];
            const u16* kr0 = Kf0 + (long)(kvbase + m) * DD;
            #pragma unroll
            for (int mt = 0; mt < 4; ++mt)
                #pragma unroll
                for (int kst = 0; kst < 2; ++kst)
                    kf[mt][kst] = *(const s16x8*)(kr0 + mt * 16 * DD + kst * 32);
            s16x8 vf[2][4];
            const u16* vr0 = Vt0 + kvbase;
            #pragma unroll
            for (int kst = 0; kst < 2; ++kst)
                #pragma unroll
                for (int dt = 0; dt < 4; ++dt)
                    vf[kst][dt] = *(const s16x8*)(vr0 + (long)dt * 16 * SS + kst * 32);

            // ---- S^T = K_tile · Q^T ----
            #pragma unroll
            for (int mt = 0; mt < 4; ++mt) {
                st[mt] = (f32x4){0.f, 0.f, 0.f, 0.f};
                #pragma unroll
                for (int kst = 0; kst < 2; ++kst)
                    st[mt] = __builtin_amdgcn_mfma_f32_16x16x32_bf16(kf[mt][kst], qf[kst], st[mt], 0, 0, 0);
            }

            // ---- causal mask (diagonal tile only) ----
            if (tile == ntiles - 1) {
                #pragma unroll
                for (int mt = 0; mt < 4; ++mt)
                    #pragma unroll
                    for (int r = 0; r < 4; ++r) {
                        const int k_g = kvbase + mt * 16 + g * 4 + r;
                        if (k_g > q_g) st[mt][r] = -1e9f;
                    }
            }

            // ---- online softmax (exp2 domain) ----
            float tm = st[0][0];
            #pragma unroll
            for (int mt = 0; mt < 4; ++mt)
                #pragma unroll
                for (int r = 0; r < 4; ++r) tm = fmaxf(tm, st[mt][r]);
            tm = fmaxf(tm, __shfl_xor(tm, 16));
            tm = fmaxf(tm, __shfl_xor(tm, 32));
            const float mnew  = fmaxf(m_run, tm);
            const float alpha = exp2f(m_run - mnew);
            float rs = 0.f;
            #pragma unroll
            for (int mt = 0; mt < 4; ++mt)
                #pragma unroll
                for (int r = 0; r < 4; ++r) {
                    const float e = exp2f(st[mt][r] - mnew);
                    st[mt][r] = e;
                    rs += e;
                }
            rs += __shfl_xor(rs, 16);
            rs += __shfl_xor(rs, 32);
            l_run = l_run * alpha + rs;
            m_run = mnew;

            unsigned pk[4][2];
            #pragma unroll
            for (int mt = 0; mt < 4; ++mt) {
                pk[mt][0] = pack_bf16(st[mt][0], st[mt][1]);
                pk[mt][1] = pack_bf16(st[mt][2], st[mt][3]);
            }

            float av[4];
            #pragma unroll
            for (int r = 0; r < 4; ++r) av[r] = __shfl(alpha, 4 * g + r);
            #pragma unroll
            for (int dt = 0; dt < 4; ++dt)
                #pragma unroll
                for (int r = 0; r < 4; ++r) o[dt][r] *= av[r];

            // ---- O += P · V (A via 2-shfl relayout, dest-side select) ----
            #pragma unroll
            for (int kst = 0; kst < 2; ++kst) {
                frag_u pa;
                #pragma unroll
                for (int ww = 0; ww < 4; ++ww) {
                    const int srcl = m + 16 * (2 * (g & 1) + (ww >> 1));
                    const int v0 = __shfl((int)pk[2 * kst][ww & 1], srcl);
                    const int v1 = __shfl((int)pk[2 * kst + 1][ww & 1], srcl);
                    pa.u[ww] = (unsigned)((g & 2) ? v1 : v0);
                }
                #pragma unroll
                for (int dt = 0; dt < 4; ++dt)
                    o[dt] = __builtin_amdgcn_mfma_f32_16x16x32_bf16(pa.s, vf[kst][dt], o[dt], 0, 0, 0);
            }
        } else {
            // ---- fallback: convert in-kernel (round-3 path) ----
            #pragma unroll
            for (int mt = 0; mt < 4; ++mt) {
                st[mt] = (f32x4){0.f, 0.f, 0.f, 0.f};
                const float* kr = Kb0 + (long)(kvbase + mt * 16 + m) * DD + g * 8;
                #pragma unroll
                for (int kst = 0; kst < 2; ++kst) {
                    f32x4 x0 = *(const f32x4*)(kr + kst * 32);
                    f32x4 x1 = *(const f32x4*)(kr + kst * 32 + 4);
                    frag_u kf;
                    kf.u[0] = pack_bf16(x0[0], x0[1]);
                    kf.u[1] = pack_bf16(x0[2], x0[3]);
                    kf.u[2] = pack_bf16(x1[0], x1[1]);
                    kf.u[3] = pack_bf16(x1[2], x1[3]);
                    st[mt] = __builtin_amdgcn_mfma_f32_16x16x32_bf16(kf.s, qf[kst], st[mt], 0, 0, 0);
                }
            }
            if (tile == ntiles - 1) {
                #pragma unroll
                for (int mt = 0; mt < 4; ++mt)
                    #pragma unroll
                    for (int r = 0; r < 4; ++r) {
                        const int k_g = kvbase + mt * 16 + g * 4 + r;
                        if (k_g > q_g) st[mt][r] = -1e9f;
                    }
            }
            float tm = st[0][0];
            #pragma unroll
            for (int mt = 0; mt < 4; ++mt)
                #pragma unroll
                for (int r = 0; r < 4; ++r) tm = fmaxf(tm, st[mt][r]);
            tm = fmaxf(tm, __shfl_xor(tm, 16));
            tm = fmaxf(tm, __shfl_xor(tm, 32));
            const float mnew  = fmaxf(m_run, tm);
            const float alpha = exp2f(m_run - mnew);
            float rs = 0.f;
            #pragma unroll
            for (int mt = 0; mt < 4; ++mt)
                #pragma unroll
                for (int r = 0; r < 4; ++r) {
                    const float e = exp2f(st[mt][r] - mnew);
                    st[mt][r] = e;
                    rs += e;
                }
            rs += __shfl_xor(rs, 16);
            rs += __shfl_xor(rs, 32);
            l_run = l_run * alpha + rs;
            m_run = mnew;

            unsigned pk[4][2];
            #pragma unroll
            for (int mt = 0; mt < 4; ++mt) {
                pk[mt][0] = pack_bf16(st[mt][0], st[mt][1]);
                pk[mt][1] = pack_bf16(st[mt][2], st[mt][3]);
            }
            float av[4];
            #pragma unroll
            for (int r = 0; r < 4; ++r) av[r] = __shfl(alpha, 4 * g + r);
            #pragma unroll
            for (int dt = 0; dt < 4; ++dt)
                #pragma unroll
                for (int r = 0; r < 4; ++r) o[dt][r] *= av[r];

            #pragma unroll
            for (int kst = 0; kst < 2; ++kst) {
                frag_u pa;
                #pragma unroll
                for (int ww = 0; ww < 4; ++ww) {
                    const int srcl = m + 16 * (2 * (g & 1) + (ww >> 1));
                    const int v0 = __shfl((int)pk[2 * kst][ww & 1], srcl);
                    const int v1 = __shfl((int)pk[2 * kst + 1][ww & 1], srcl);
                    pa.u[ww] = (unsigned)((g & 2) ? v1 : v0);
                }
                const float* vcol = Vb0 + (long)(kvbase + kst * 32 + g * 8) * DD + m;
                #pragma unroll
                for (int dt = 0; dt < 4; ++dt) {
                    const float* vc = vcol + dt * 16;
                    frag_u vb;
                    #pragma unroll
                    for (int jj = 0; jj < 4; ++jj)
                        vb.u[jj] = pack_bf16(vc[(2 * jj) * DD], vc[(2 * jj + 1) * DD]);
                    o[dt] = __builtin_amdgcn_mfma_f32_16x16x32_bf16(pa.s, vb.s, o[dt], 0, 0, 0);
                }
            }
        }
    }

    // ---- merge tree across the 8 waves ----
    for (int half = 4; half >= 1; half >>= 1) {
        if (w >= half && w < 2 * half) {
            const int slot = w - half;
            if (g == 0) { smM[slot][m] = m_run; smL[slot][m] = l_run; }
            #pragma unroll
            for (int dt = 0; dt < 4; ++dt)
                #pragma unroll
                for (int r = 0; r < 4; ++r)
                    mbuf[slot][(4 * g + r) * 68 + 16 * dt + m] = o[dt][r];
        }
        __syncthreads();
        if (w < half) {
            const float m2 = smM[w][m], l2 = smL[w][m];
            const float mn = fmaxf(m_run, m2);
            const float a1 = exp2f(m_run - mn);
            const float a2 = exp2f(m2 - mn);
            l_run = l_run * a1 + l2 * a2;
            m_run = mn;
            float av1[4], av2[4];
            #pragma unroll
            for (int r = 0; r < 4; ++r) {
                av1[r] = __shfl(a1, 4 * g + r);
                av2[r] = __shfl(a2, 4 * g + r);
            }
            #pragma unroll
            for (int dt = 0; dt < 4; ++dt)
                #pragma unroll
                for (int r = 0; r < 4; ++r)
                    o[dt][r] = o[dt][r] * av1[r] +
                               mbuf[w][(4 * g + r) * 68 + 16 * dt + m] * av2[r];
        }
        __syncthreads();
    }

    // ---- epilogue ----
    if (w == 0) {
        float lv[4];
        #pragma unroll
        for (int r = 0; r < 4; ++r) lv[r] = 1.0f / __shfl(l_run, 4 * g + r);
        float* Ob = O + ((long)b * SS + q0) * DD;
        #pragma unroll
        for (int dt = 0; dt < 4; ++dt)
            #pragma unroll
            for (int r = 0; r < 4; ++r)
                Ob[(4 * g + r) * DD + dt * 16 + m] = o[dt][r] * lv[r];
    }
}

extern "C" void kernel_launch(void* const* d_in, const int* in_sizes, int n_in,
                              void* d_out, int out_size, void* d_ws, size_t ws_size,
                              hipStream_t stream) {
    const float* Q = (const float*)d_in[0];
    const float* K = (const float*)d_in[1];
    const float* V = (const float*)d_in[2];
    float* O = (float*)d_out;
    const size_t tensor_b = (size_t)BB * SS * DD * sizeof(u16);   // 2 MiB
    if (ws_size >= 2 * tensor_b) {
        u16* Kbf = (u16*)d_ws;
        u16* VT  = (u16*)((char*)d_ws + tensor_b);
        conv_k <<<dim3(BB * SS * DD / 8 / 256), dim3(256), 0, stream>>>(K, Kbf);
        conv_vt<<<dim3(BB * (SS / 64)),        dim3(256), 0, stream>>>(V, VT);
        attn_fwd<true><<<dim3(BB * (SS / 16)), dim3(512), 0, stream>>>(Q, K, V, O, Kbf, VT);
    } else {
        attn_fwd<false><<<dim3(BB * (SS / 16)), dim3(512), 0, stream>>>(Q, K, V, O, nullptr, nullptr);
    }
}